// Round 13
// baseline (237.456 us; speedup 1.0000x reference)
//
#include <hip/hip_runtime.h>
#include <cstdint>
#include <cstddef>

typedef __attribute__((ext_vector_type(8))) __bf16 bf16x8;
typedef __attribute__((ext_vector_type(4))) __bf16 bf16x4;
typedef __attribute__((ext_vector_type(4))) float  f32x4;

#define NPIX 4096
#define CHN  256

__device__ __forceinline__ void async_copy16(void* lds, const void* g) {
  __builtin_amdgcn_global_load_lds(
      (const __attribute__((address_space(1))) unsigned int*)g,
      (__attribute__((address_space(3))) unsigned int*)lds, 16, 0, 0);
}

// ---------- transpose + cast: x[B,C,N] f32 -> xT[B,N,C] bf16 ----------
__global__ __launch_bounds__(256) void k_transpose_cast(
    const float* __restrict__ X, __bf16* __restrict__ xT)
{
  __shared__ float tile[64][65];
  const int bid = blockIdx.x;
  const int b  = bid >> 8;
  const int pt = (bid >> 2) & 63;
  const int ct = bid & 3;
  const int tid = threadIdx.x;
  const int tc = tid & 63, tr = tid >> 6;
  const float* Xb = X + ((size_t)b*CHN + ct*64)*NPIX + pt*64;
#pragma unroll
  for (int i=0;i<16;++i) {
    int row = tr + i*4;
    tile[row][tc] = Xb[(size_t)row*NPIX + tc];
  }
  __syncthreads();
  __bf16* Tb = xT + ((size_t)b*NPIX + pt*64)*CHN + ct*64;
#pragma unroll
  for (int i=0;i<16;++i) {
    int prow = tr + i*4;
    Tb[(size_t)prow*CHN + tc] = (__bf16)tile[tc][prow];
  }
}

// ---------- weights: [O,I,3,3] f32 -> [tap][O][I] bf16, both convs ----------
__global__ __launch_bounds__(256) void k_wcast(
    const float* __restrict__ wv, const float* __restrict__ ww,
    __bf16* __restrict__ wvt, __bf16* __restrict__ wwt)
{
  int idx = blockIdx.x*256 + threadIdx.x;
  int t = idx >> 16;
  int o = (idx >> 8) & 255;
  int i = idx & 255;
  size_t src = ((size_t)o*256 + i)*9 + t;
  wvt[idx] = (__bf16)wv[src];
  wwt[idx] = (__bf16)ww[src];
}

// ---------- conv3x3 as 9-tap GEMM, 128x128 tile, 8 waves, dbuf ----------
// Epilogue also emits per-channel partial BN stats (sum, sumsq over this
// block's pixels, computed from the bf16-rounded outputs) into
// PS/PS2[contrib][c] — no atomics, deterministic; finalized by k_bn_finalize.
__global__ __launch_bounds__(512, 1) void k_conv_tap(
    const __bf16* __restrict__ W9,   // [9][256][256]
    const __bf16* __restrict__ Bt,   // [B][4096][256] pixel-major
    const __bf16* __restrict__ zb,   // zero page (>=16B)
    __bf16* __restrict__ Y,          // [B][256][4096] bf16
    float* __restrict__ PS,          // [256 contrib][256 ch] partial sums
    float* __restrict__ PS2)         // [256 contrib][256 ch] partial sumsq
{
  __shared__ __bf16 Alds[2][128*64];
  __shared__ __bf16 Blds[2][128*64];
  const int bid0 = blockIdx.x;
  const int bid = (bid0 & 7)*32 + (bid0 >> 3);   // XCD chunk swizzle (256)
  const int b  = bid >> 6;
  const int mt = (bid >> 5) & 1;
  const int nt = bid & 31;
  const int m0 = mt << 7;
  const int p0 = nt << 7;
  const int tid = threadIdx.x;
  const int w = tid >> 6, l = tid & 63;
  const int l15 = l & 15, lhi = l >> 4;
  const int wr = (w >> 1) << 5;     // 0/32/64/96
  const int wc = (w & 1) << 6;      // 0/64

  const __bf16* Btb = Bt + ((size_t)b << 20);
  const f32x4 vzero = {0.f,0.f,0.f,0.f};
  f32x4 acc[2][4];
#pragma unroll
  for (int i=0;i<2;++i)
#pragma unroll
    for (int j=0;j<4;++j) acc[i][j] = vzero;

  auto stage = [&](int buf, int it) {
    const int t = it >> 2, kc = it & 3;
    const int dy = t/3 - 1, dx = t%3 - 1;
    const int dq = dy*64 + dx;
    const int k0 = kc << 6;
    // A tile 128x64 (16 insts, 2/wave), source chunk-XOR-swizzled
#pragma unroll
    for (int i=0;i<2;++i) {
      int inst = w*2 + i;
      int s = inst*64 + l;
      int row = s >> 3, ch = s & 7;
      const __bf16* g = W9 + (size_t)t*65536 + (size_t)(m0+row)*256 + k0
                        + ((ch ^ (row & 7)) << 3);
      async_copy16((char*)(&Alds[buf][0]) + inst*1024, g);
    }
    // B tile 128x64 (16 insts, 2/wave), border-masked via zero page, swizzled
#pragma unroll
    for (int i=0;i<2;++i) {
      int inst = w*2 + i;
      int s = inst*64 + l;
      int pp = s >> 3, ch = s & 7;
      int p = p0 + pp;
      int xx = (p & 63) + dx;
      int yy = (p >> 6) + dy;
      bool ok = ((unsigned)xx < 64u) & ((unsigned)yy < 64u);
      const __bf16* g = ok ? (Btb + (size_t)(p + dq)*256 + k0 + ((ch ^ (pp & 7)) << 3))
                           : zb;
      async_copy16((char*)(&Blds[buf][0]) + inst*1024, g);
    }
  };

  stage(0, 0);
#pragma unroll 1
  for (int it=0; it<36; ++it) {
    const int cur = it & 1;
    if (it < 35) {
      stage(cur^1, it+1);
      asm volatile("s_waitcnt vmcnt(4)" ::: "memory");
    } else {
      asm volatile("s_waitcnt vmcnt(0)" ::: "memory");
    }
    __builtin_amdgcn_s_barrier();
    __builtin_amdgcn_sched_barrier(0);

    const char* Ac = (const char*)(&Alds[cur][0]);
    const char* Bc = (const char*)(&Blds[cur][0]);
#pragma unroll
    for (int kk=0; kk<2; ++kk) {
      const int swz = (((kk<<2)+lhi) ^ (l15 & 7)) << 4;
      bf16x8 af[2], bfr[4];
#pragma unroll
      for (int i=0;i<2;++i)
        af[i] = *(const bf16x8*)(Ac + (size_t)(wr + 16*i + l15)*128 + swz);
#pragma unroll
      for (int j=0;j<4;++j)
        bfr[j] = *(const bf16x8*)(Bc + (size_t)(wc + 16*j + l15)*128 + swz);
#pragma unroll
      for (int i=0;i<2;++i)
#pragma unroll
        for (int j=0;j<4;++j)
          acc[i][j] = __builtin_amdgcn_mfma_f32_16x16x32_bf16(af[i], bfr[j], acc[i][j], 0,0,0);
    }
    __builtin_amdgcn_s_barrier();
  }

  __bf16* Yb = Y + ((size_t)b << 20);
  float ps[2][4], ps2[2][4];
#pragma unroll
  for (int i=0;i<2;++i)
#pragma unroll
    for (int r=0;r<4;++r) { ps[i][r] = 0.f; ps2[i][r] = 0.f; }
#pragma unroll
  for (int i=0;i<2;++i)
#pragma unroll
    for (int j=0;j<4;++j)
#pragma unroll
      for (int r=0;r<4;++r) {
        int row = m0 + wr + 16*i + lhi*4 + r;
        int col = p0 + wc + 16*j + l15;
        __bf16 vb16 = (__bf16)acc[i][j][r];
        float v = (float)vb16;
        ps[i][r]  += v;
        ps2[i][r] += v*v;
        Yb[(size_t)row*NPIX + col] = vb16;
      }
  // reduce partials across the 16 l15 lanes (this wave's 64-pixel half)
#pragma unroll
  for (int i=0;i<2;++i)
#pragma unroll
    for (int r=0;r<4;++r)
#pragma unroll
      for (int d=1; d<16; d<<=1) {
        ps[i][r]  += __shfl_xor(ps[i][r],  d, 64);
        ps2[i][r] += __shfl_xor(ps2[i][r], d, 64);
      }
  if (l15 == 0) {
    const int contrib = b*64 + nt*2 + (wc >> 6);
#pragma unroll
    for (int i=0;i<2;++i)
#pragma unroll
      for (int r=0;r<4;++r) {
        int c = m0 + wr + 16*i + lhi*4 + r;
        PS [contrib*256 + c] = ps[i][r];
        PS2[contrib*256 + c] = ps2[i][r];
      }
  }
}

// ---------- finalize BN stats: reduce 256 partials/channel -> scale/shift ----
__global__ __launch_bounds__(256) void k_bn_finalize(
    const float* __restrict__ PS, const float* __restrict__ PS2,
    const float* __restrict__ gamma, const float* __restrict__ beta,
    float* __restrict__ scale, float* __restrict__ shift)
{
  const int c = threadIdx.x;
  float S = 0.f, S2 = 0.f;
#pragma unroll 4
  for (int k=0;k<256;++k) {
    S  += PS [k*256 + c];
    S2 += PS2[k*256 + c];
  }
  const float inv_n = 1.f/16384.f;
  float mean = S*inv_n;
  float var  = S2*inv_n - mean*mean;
  float rstd = rsqrtf(var + 1e-5f);
  float sc = gamma[c]*rstd;
  scale[c] = sc;
  shift[c] = beta[c] - mean*sc;
}

// ---------- apply BN + relu: bf16 Y -> f32 out ----------
__global__ __launch_bounds__(256) void k_bn_relu(
    const __bf16* __restrict__ Y, const float* __restrict__ scale,
    const float* __restrict__ shift, float* __restrict__ out)
{
  size_t idx = ((size_t)blockIdx.x*256 + threadIdx.x)*8;
  int c = (int)((idx >> 12) & 255);
  bf16x8 v = *(const bf16x8*)(Y + idx);
  float sc = scale[c], sh = shift[c];
  float4 r0, r1;
  r0.x = fmaxf((float)v[0]*sc + sh, 0.f);
  r0.y = fmaxf((float)v[1]*sc + sh, 0.f);
  r0.z = fmaxf((float)v[2]*sc + sh, 0.f);
  r0.w = fmaxf((float)v[3]*sc + sh, 0.f);
  r1.x = fmaxf((float)v[4]*sc + sh, 0.f);
  r1.y = fmaxf((float)v[5]*sc + sh, 0.f);
  r1.z = fmaxf((float)v[6]*sc + sh, 0.f);
  r1.w = fmaxf((float)v[7]*sc + sh, 0.f);
  *(float4*)(out + idx)     = r0;
  *(float4*)(out + idx + 4) = r1;
}

// ---------- flash attention (proven 112.5us structure) + fused value-BN ----
// V input is the RAW conv1 output y; BN commutes with attention exactly:
// softmax(S) @ (y*sc+sh) = sc*(softmax(S)@y) + sh  (per output channel c).
// roles: qh = w&1 (32 q), kvq = w>>1 (16 kv for QK), p = kvq>>1 (32-kv PV
// window), cfh = kvq&1 (128-c PV half). No-max softmax (S bounded ~24).
__global__ __launch_bounds__(512, 2) void k_attn(
    const __bf16* __restrict__ xT,   // [B][N][C]
    const __bf16* __restrict__ val,  // [B][C][N] raw conv1 out
    const float* __restrict__ scale, // [C] BN scale (value branch)
    const float* __restrict__ shift, // [C] BN shift
    __bf16* __restrict__ O)          // [B][N][C]
{
  // K dbuf 2x32KB @0 | V dbuf 2x32KB @65536 | Pscr 4x2560B @131072 = 141312
  // epilogue reuses [0,65536) for O partials and @65536 for lsum
  __shared__ __align__(16) char smem[141312];

  const int bid0 = blockIdx.x;
  const int bid = (bid0 & 7)*32 + (bid0 >> 3);  // XCD chunk swizzle
  const int b  = bid >> 6;
  const int q0 = (bid & 63) << 6;
  const int tid = threadIdx.x;
  const int w = tid >> 6, l = tid & 63;
  const int l15 = l & 15, lhi = l >> 4;
  const int qh  = w & 1;          // 32 q-rows
  const int kvq = w >> 1;         // 16 kv-rows (QK)
  const int p   = kvq >> 1;       // 32-kv window (PV)
  const int cfh = kvq & 1;        // 128-c half (PV)

  const __bf16* xTb = xT  + ((size_t)b << 20);
  const __bf16* vb  = val + ((size_t)b << 20);

  // Q: 32 rows/wave in registers, pre-scaled by C^-0.5 = 1/16 (exact)
  bf16x8 aq[2][8];
#pragma unroll
  for (int rg=0; rg<2; ++rg) {
    const __bf16* qp = xTb + (size_t)(q0 + qh*32 + rg*16 + l15)*256 + lhi*8;
#pragma unroll
    for (int kc=0; kc<8; ++kc) {
      bf16x8 v = *(const bf16x8*)(qp + kc*32);
#pragma unroll
      for (int j=0;j<8;++j) v[j] = (__bf16)((float)v[j] * 0.0625f);
      aq[rg][kc] = v;
    }
  }

  auto stage = [&](int buf, int m0) {
    char* kb = smem + buf*32768;
    char* vv = smem + 65536 + buf*32768;
#pragma unroll
    for (int i=0;i<4;++i) {          // K: 4 insts/wave (32 total)
      int inst = w*4 + i;
      int s = inst*64 + l;
      int row = s >> 5, cs = s & 31;
      const __bf16* g = xTb + (size_t)(m0 + row)*256 + ((cs ^ (row & 7)) << 3);
      async_copy16(kb + inst*1024, g);
    }
#pragma unroll
    for (int i=0;i<4;++i) {          // V: 4 insts/wave (32 total)
      int inst = w*4 + i;
      int s = inst*64 + l;
      int row = s >> 3, cs = s & 7;
      const __bf16* g = vb + (size_t)row*NPIX + m0 + ((cs ^ (row & 7)) << 3);
      async_copy16(vv + inst*1024, g);
    }
  };

  const f32x4 vzero = {0.f,0.f,0.f,0.f};
  float lsum[2][4];
#pragma unroll
  for (int rg=0;rg<2;++rg)
#pragma unroll
    for (int r=0;r<4;++r) lsum[rg][r] = 0.f;
  f32x4 o[2][8];
#pragma unroll
  for (int rg=0;rg<2;++rg)
#pragma unroll
    for (int cf=0; cf<8; ++cf) o[rg][cf] = vzero;

  stage(0, 0);

#pragma unroll 1
  for (int mt=0; mt<64; ++mt) {
    const int cur = mt & 1;
    asm volatile("s_waitcnt vmcnt(0)" ::: "memory");
    __builtin_amdgcn_s_barrier();
    __builtin_amdgcn_sched_barrier(0);
    if (mt < 63) stage(cur^1, (mt+1) << 6);   // flies under compute below

    const char* Kc = smem + cur*32768;
    const char* Vc = smem + 65536 + cur*32768;
    __bf16* pReg = (__bf16*)(smem + 131072 + (qh*2 + p)*2560); // [32q][40]

    // S = Q K^T : rows n = qh*32+rg*16+lhi*4+r, cols m = kvq*16+l15
    f32x4 s4[2];
    s4[0] = vzero; s4[1] = vzero;
    {
      const int krow = kvq*16 + l15;
      const char* kbase = Kc + krow*512;
#pragma unroll
      for (int kc=0; kc<8; ++kc) {
        bf16x8 bk = *(const bf16x8*)(kbase + ((((kc<<2)+lhi) ^ (krow&7)) << 4));
        s4[0] = __builtin_amdgcn_mfma_f32_16x16x32_bf16(aq[0][kc], bk, s4[0], 0,0,0);
        s4[1] = __builtin_amdgcn_mfma_f32_16x16x32_bf16(aq[1][kc], bk, s4[1], 0,0,0);
      }
    }

    // P = exp(S) -> pair-shared region (this wave's 16-kv half)
#pragma unroll
    for (int rg=0;rg<2;++rg)
#pragma unroll
      for (int r=0;r<4;++r) {
        float pv = __expf(s4[rg][r]);
        __bf16 pbf = (__bf16)pv;
        pReg[(rg*16 + lhi*4 + r)*40 + cfh*16 + l15] = pbf;
        lsum[rg][r] += (float)pbf;
      }

    // hand off P within kv-pair
    asm volatile("s_waitcnt lgkmcnt(0)" ::: "memory");
    __builtin_amdgcn_s_barrier();
    __builtin_amdgcn_sched_barrier(0);

    // full 32-kv P fragments (both halves of the pair)
    bf16x8 pa0 = *(const bf16x8*)(pReg + (size_t)l15*40 + lhi*8);
    bf16x8 pa1 = *(const bf16x8*)(pReg + (size_t)(16 + l15)*40 + lhi*8);

    // O += P V : cols c = cfh*128 + cf*16 + l15, K = pair's 32 kv
#pragma unroll
    for (int cf=0; cf<8; ++cf) {
      const int c = cfh*128 + (cf<<4) + l15;
      const char* vbase = Vc + c*128;
      bf16x8 bv = *(const bf16x8*)(vbase + ((((p<<2)+lhi) ^ (c&7)) << 4));
      o[0][cf] = __builtin_amdgcn_mfma_f32_16x16x32_bf16(pa0, bv, o[0][cf], 0,0,0);
      o[1][cf] = __builtin_amdgcn_mfma_f32_16x16x32_bf16(pa1, bv, o[1][cf], 0,0,0);
    }
  }

  // reduce lsum across the 16 l15 lanes (sum over this wave's 16 kv columns)
#pragma unroll
  for (int rg=0;rg<2;++rg)
#pragma unroll
    for (int r=0;r<4;++r)
#pragma unroll
      for (int d=1; d<16; d<<=1) lsum[rg][r] += __shfl_xor(lsum[rg][r], d, 64);

  __builtin_amdgcn_s_barrier();           // everyone done with K/V/P buffers
  float* oscr = (float*)smem;             // 4 regions (qh,cfh) x 32x128 f32
  float* lscr = (float*)(smem + 65536);   // 8 waves x 32 f32
  if (l15 == 0) {
#pragma unroll
    for (int rg=0;rg<2;++rg)
#pragma unroll
      for (int r=0;r<4;++r)
        lscr[w*32 + rg*16 + lhi*4 + r] = lsum[rg][r];
  }
  if (p == 1) {
    float* od = oscr + (size_t)(qh*2 + cfh)*4096;
#pragma unroll
    for (int rg=0;rg<2;++rg)
#pragma unroll
      for (int cf=0;cf<8;++cf)
#pragma unroll
        for (int r=0;r<4;++r)
          od[(rg*16 + lhi*4 + r)*128 + (cf<<4) + l15] = o[rg][cf][r];
  }
  asm volatile("s_waitcnt lgkmcnt(0)" ::: "memory");
  __builtin_amdgcn_s_barrier();
  if (p == 0) {
    const float* od = oscr + (size_t)(qh*2 + cfh)*4096;
    __bf16* Ob = O + ((size_t)b << 20);
#pragma unroll
    for (int rg=0;rg<2;++rg) {
      float inv[4];
#pragma unroll
      for (int r=0;r<4;++r) {
        float tot = 0.f;
#pragma unroll
        for (int k=0;k<4;++k)
          tot += lscr[(qh + 2*k)*32 + rg*16 + lhi*4 + r];
        inv[r] = 1.f / tot;
      }
#pragma unroll
      for (int cf=0;cf<8;++cf) {
        const int c = cfh*128 + (cf<<4) + l15;
        const float sc = scale[c], sh = shift[c];
#pragma unroll
        for (int r=0;r<4;++r) {
          float vtot = o[rg][cf][r] + od[(rg*16 + lhi*4 + r)*128 + (cf<<4) + l15];
          int row = q0 + qh*32 + rg*16 + lhi*4 + r;
          Ob[(size_t)row*256 + c] = (__bf16)(vtot * inv[r] * sc + sh);
        }
      }
    }
  }
}

extern "C" void kernel_launch(void* const* d_in, const int* in_sizes, int n_in,
                              void* d_out, int out_size, void* d_ws, size_t ws_size,
                              hipStream_t stream)
{
  const float* x     = (const float*)d_in[0];
  const float* wv    = (const float*)d_in[1];
  // d_in[2] = bv: bias shifts BN mean by the same amount -> cancels exactly
  const float* gv    = (const float*)d_in[3];
  const float* betav = (const float*)d_in[4];
  const float* ww    = (const float*)d_in[5];
  // d_in[6] = bw: cancels likewise
  const float* gw    = (const float*)d_in[7];
  const float* betaw = (const float*)d_in[8];
  float* out = (float*)d_out;

  char* ws = (char*)d_ws;
  __bf16* xT     = (__bf16*)(ws);                 // 8 MiB [B][N][C]
  __bf16* Obuf   = (__bf16*)(ws + 8388608);       // 8 MiB [B][N][C]
  __bf16* ybuf   = (__bf16*)(ws + 16777216);      // 8 MiB [B][C][N] conv out
  __bf16* wvt    = (__bf16*)(ws + 25165824);      // 1.125 MiB [9][O][I]
  __bf16* wwt    = (__bf16*)(ws + 26345472);      // 1.125 MiB
  float* scale_v = (float*)(ws + 27525120);
  float* shift_v = (float*)(ws + 27526144);
  float* scale_w = (float*)(ws + 27527168);
  float* shift_w = (float*)(ws + 27528192);
  __bf16* zbuf   = (__bf16*)(ws + 27529216);      // 1 KiB zero page
  float* part_s  = (float*)(ws + 27530240);       // 256 KiB [256][256]
  float* part_s2 = (float*)(ws + 27792384);       // 256 KiB [256][256]
  if (ws_size < 28054528) return;

  hipMemsetAsync(zbuf, 0, 1024, stream);

  k_transpose_cast<<<1024, 256, 0, stream>>>(x, xT);
  k_wcast<<<2304, 256, 0, stream>>>(wv, ww, wvt, wwt);

  // value branch: conv1 (stats fused into epilogue) + finalize
  k_conv_tap<<<256, 512, 0, stream>>>(wvt, xT, zbuf, ybuf, part_s, part_s2);
  k_bn_finalize<<<1, 256, 0, stream>>>(part_s, part_s2, gv, betav, scale_v, shift_v);

  // attention (consumes raw conv1 out + BN scale/shift)
  k_attn<<<256, 512, 0, stream>>>(xT, ybuf, scale_v, shift_v, Obuf);

  // output branch: conv2 (stats fused) + finalize + BN+relu
  k_conv_tap<<<256, 512, 0, stream>>>(wwt, Obuf, zbuf, ybuf, part_s, part_s2);
  k_bn_finalize<<<1, 256, 0, stream>>>(part_s, part_s2, gw, betaw, scale_w, shift_w);
  k_bn_relu<<<2048, 256, 0, stream>>>(ybuf, scale_w, shift_w, out);
}

// Round 14
// 195.639 us; speedup vs baseline: 1.2137x; 1.2137x over previous
//
#include <hip/hip_runtime.h>
#include <cstdint>
#include <cstddef>

typedef __attribute__((ext_vector_type(8))) __bf16 bf16x8;
typedef __attribute__((ext_vector_type(4))) __bf16 bf16x4;
typedef __attribute__((ext_vector_type(4))) float  f32x4;

#define NPIX 4096
#define CHN  256

__device__ __forceinline__ void async_copy16(void* lds, const void* g) {
  __builtin_amdgcn_global_load_lds(
      (const __attribute__((address_space(1))) unsigned int*)g,
      (__attribute__((address_space(3))) unsigned int*)lds, 16, 0, 0);
}

// ---------- prep: transpose+cast x -> xT (blocks 0..1023), wcast (1024..3327)
__global__ __launch_bounds__(256) void k_prep(
    const float* __restrict__ X, __bf16* __restrict__ xT,
    const float* __restrict__ wv, const float* __restrict__ ww,
    __bf16* __restrict__ wvt, __bf16* __restrict__ wwt)
{
  __shared__ float tile[64][65];
  const int bid0 = blockIdx.x;
  const int tid = threadIdx.x;
  if (bid0 >= 1024) {
    int idx = (bid0 - 1024)*256 + tid;   // 589824 = 9*256*256 exactly
    int t = idx >> 16;
    int o = (idx >> 8) & 255;
    int i = idx & 255;
    size_t src = ((size_t)o*256 + i)*9 + t;
    wvt[idx] = (__bf16)wv[src];
    wwt[idx] = (__bf16)ww[src];
    return;
  }
  const int bid = bid0;
  const int b  = bid >> 8;
  const int pt = (bid >> 2) & 63;
  const int ct = bid & 3;
  const int tc = tid & 63, tr = tid >> 6;
  const float* Xb = X + ((size_t)b*CHN + ct*64)*NPIX + pt*64;
#pragma unroll
  for (int i=0;i<16;++i) {
    int row = tr + i*4;
    tile[row][tc] = Xb[(size_t)row*NPIX + tc];
  }
  __syncthreads();
  __bf16* Tb = xT + ((size_t)b*NPIX + pt*64)*CHN + ct*64;
#pragma unroll
  for (int i=0;i<16;++i) {
    int prow = tr + i*4;
    Tb[(size_t)prow*CHN + tc] = (__bf16)tile[tc][prow];
  }
}

// ---------- conv3x3 as 9-tap GEMM, 128x128 tile, 8 waves, dbuf ----------
__global__ __launch_bounds__(512, 1) void k_conv_tap(
    const __bf16* __restrict__ W9,   // [9][256][256]
    const __bf16* __restrict__ Bt,   // [B][4096][256] pixel-major
    const __bf16* __restrict__ zb,   // zero page (>=16B)
    __bf16* __restrict__ Y)          // [B][256][4096] bf16
{
  __shared__ __bf16 Alds[2][128*64];
  __shared__ __bf16 Blds[2][128*64];
  const int bid0 = blockIdx.x;
  const int bid = (bid0 & 7)*32 + (bid0 >> 3);   // XCD chunk swizzle (256)
  const int b  = bid >> 6;
  const int mt = (bid >> 5) & 1;
  const int nt = bid & 31;
  const int m0 = mt << 7;
  const int p0 = nt << 7;
  const int tid = threadIdx.x;
  const int w = tid >> 6, l = tid & 63;
  const int l15 = l & 15, lhi = l >> 4;
  const int wr = (w >> 1) << 5;     // 0/32/64/96
  const int wc = (w & 1) << 6;      // 0/64

  const __bf16* Btb = Bt + ((size_t)b << 20);
  const f32x4 vzero = {0.f,0.f,0.f,0.f};
  f32x4 acc[2][4];
#pragma unroll
  for (int i=0;i<2;++i)
#pragma unroll
    for (int j=0;j<4;++j) acc[i][j] = vzero;

  auto stage = [&](int buf, int it) {
    const int t = it >> 2, kc = it & 3;
    const int dy = t/3 - 1, dx = t%3 - 1;
    const int dq = dy*64 + dx;
    const int k0 = kc << 6;
    // A tile 128x64 (16 insts, 2/wave), source chunk-XOR-swizzled
#pragma unroll
    for (int i=0;i<2;++i) {
      int inst = w*2 + i;
      int s = inst*64 + l;
      int row = s >> 3, ch = s & 7;
      const __bf16* g = W9 + (size_t)t*65536 + (size_t)(m0+row)*256 + k0
                        + ((ch ^ (row & 7)) << 3);
      async_copy16((char*)(&Alds[buf][0]) + inst*1024, g);
    }
    // B tile 128x64 (16 insts, 2/wave), border-masked via zero page, swizzled
#pragma unroll
    for (int i=0;i<2;++i) {
      int inst = w*2 + i;
      int s = inst*64 + l;
      int pp = s >> 3, ch = s & 7;
      int p = p0 + pp;
      int xx = (p & 63) + dx;
      int yy = (p >> 6) + dy;
      bool ok = ((unsigned)xx < 64u) & ((unsigned)yy < 64u);
      const __bf16* g = ok ? (Btb + (size_t)(p + dq)*256 + k0 + ((ch ^ (pp & 7)) << 3))
                           : zb;
      async_copy16((char*)(&Blds[buf][0]) + inst*1024, g);
    }
  };

  stage(0, 0);
#pragma unroll 1
  for (int it=0; it<36; ++it) {
    const int cur = it & 1;
    if (it < 35) {
      stage(cur^1, it+1);
      asm volatile("s_waitcnt vmcnt(4)" ::: "memory");
    } else {
      asm volatile("s_waitcnt vmcnt(0)" ::: "memory");
    }
    __builtin_amdgcn_s_barrier();
    __builtin_amdgcn_sched_barrier(0);

    const char* Ac = (const char*)(&Alds[cur][0]);
    const char* Bc = (const char*)(&Blds[cur][0]);
#pragma unroll
    for (int kk=0; kk<2; ++kk) {
      const int swz = (((kk<<2)+lhi) ^ (l15 & 7)) << 4;
      bf16x8 af[2], bfr[4];
#pragma unroll
      for (int i=0;i<2;++i)
        af[i] = *(const bf16x8*)(Ac + (size_t)(wr + 16*i + l15)*128 + swz);
#pragma unroll
      for (int j=0;j<4;++j)
        bfr[j] = *(const bf16x8*)(Bc + (size_t)(wc + 16*j + l15)*128 + swz);
#pragma unroll
      for (int i=0;i<2;++i)
#pragma unroll
        for (int j=0;j<4;++j)
          acc[i][j] = __builtin_amdgcn_mfma_f32_16x16x32_bf16(af[i], bfr[j], acc[i][j], 0,0,0);
    }
    __builtin_amdgcn_s_barrier();
  }

  __bf16* Yb = Y + ((size_t)b << 20);
#pragma unroll
  for (int i=0;i<2;++i)
#pragma unroll
    for (int j=0;j<4;++j)
#pragma unroll
      for (int r=0;r<4;++r) {
        int row = m0 + wr + 16*i + lhi*4 + r;
        int col = p0 + wc + 16*j + l15;
        Yb[(size_t)row*NPIX + col] = (__bf16)acc[i][j][r];
      }
}

// ---------- BN stats from bf16 Y -> folded scale/shift ----------
__global__ __launch_bounds__(256) void k_bn_stats(
    const __bf16* __restrict__ Y, const float* __restrict__ gamma,
    const float* __restrict__ beta, float* __restrict__ scale,
    float* __restrict__ shift)
{
  const int c = blockIdx.x;
  const int tid = threadIdx.x;
  float s = 0.f, s2 = 0.f;
#pragma unroll 1
  for (int b=0;b<4;++b) {
    const __bf16* p = Y + ((size_t)b*CHN + c)*NPIX;
#pragma unroll
    for (int i=0;i<2;++i) {
      bf16x8 v = *(const bf16x8*)(p + (tid + i*256)*8);
#pragma unroll
      for (int j=0;j<8;++j) { float f = (float)v[j]; s += f; s2 += f*f; }
    }
  }
#pragma unroll
  for (int d=1; d<64; d<<=1) { s += __shfl_xor(s, d, 64); s2 += __shfl_xor(s2, d, 64); }
  __shared__ float rs[4], rs2[4];
  if ((tid & 63) == 0) { rs[tid>>6] = s; rs2[tid>>6] = s2; }
  __syncthreads();
  if (tid == 0) {
    float S  = rs[0]+rs[1]+rs[2]+rs[3];
    float S2 = rs2[0]+rs2[1]+rs2[2]+rs2[3];
    const float inv_n = 1.f/16384.f;
    float mean = S*inv_n;
    float var  = S2*inv_n - mean*mean;
    float rstd = rsqrtf(var + 1e-5f);
    float sc = gamma[c]*rstd;
    scale[c] = sc;
    shift[c] = beta[c] - mean*sc;
  }
}

// ---------- apply BN + relu: bf16 Y -> f32 out ----------
__global__ __launch_bounds__(256) void k_bn_relu(
    const __bf16* __restrict__ Y, const float* __restrict__ scale,
    const float* __restrict__ shift, float* __restrict__ out)
{
  size_t idx = ((size_t)blockIdx.x*256 + threadIdx.x)*8;
  int c = (int)((idx >> 12) & 255);
  bf16x8 v = *(const bf16x8*)(Y + idx);
  float sc = scale[c], sh = shift[c];
  float4 r0, r1;
  r0.x = fmaxf((float)v[0]*sc + sh, 0.f);
  r0.y = fmaxf((float)v[1]*sc + sh, 0.f);
  r0.z = fmaxf((float)v[2]*sc + sh, 0.f);
  r0.w = fmaxf((float)v[3]*sc + sh, 0.f);
  r1.x = fmaxf((float)v[4]*sc + sh, 0.f);
  r1.y = fmaxf((float)v[5]*sc + sh, 0.f);
  r1.z = fmaxf((float)v[6]*sc + sh, 0.f);
  r1.w = fmaxf((float)v[7]*sc + sh, 0.f);
  *(float4*)(out + idx)     = r0;
  *(float4*)(out + idx + 4) = r1;
}

// ---------- flash attention (proven 112.5us structure) + fused value-BN ----
// V input is the RAW conv1 output y; BN commutes with attention exactly:
// softmax(S) @ (y*sc+sh) = sc*(softmax(S)@y) + sh  (per output channel c).
// roles: qh = w&1 (32 q), kvq = w>>1 (16 kv for QK), p = kvq>>1 (32-kv PV
// window), cfh = kvq&1 (128-c PV half). No-max softmax (S bounded ~24).
__global__ __launch_bounds__(512, 2) void k_attn(
    const __bf16* __restrict__ xT,   // [B][N][C]
    const __bf16* __restrict__ val,  // [B][C][N] raw conv1 out
    const float* __restrict__ scale, // [C] BN scale (value branch)
    const float* __restrict__ shift, // [C] BN shift
    __bf16* __restrict__ O)          // [B][N][C]
{
  // K dbuf 2x32KB @0 | V dbuf 2x32KB @65536 | Pscr 4x2560B @131072 = 141312
  // epilogue reuses [0,65536) for O partials and @65536 for lsum
  __shared__ __align__(16) char smem[141312];

  const int bid0 = blockIdx.x;
  const int bid = (bid0 & 7)*32 + (bid0 >> 3);  // XCD chunk swizzle
  const int b  = bid >> 6;
  const int q0 = (bid & 63) << 6;
  const int tid = threadIdx.x;
  const int w = tid >> 6, l = tid & 63;
  const int l15 = l & 15, lhi = l >> 4;
  const int qh  = w & 1;          // 32 q-rows
  const int kvq = w >> 1;         // 16 kv-rows (QK)
  const int p   = kvq >> 1;       // 32-kv window (PV)
  const int cfh = kvq & 1;        // 128-c half (PV)

  const __bf16* xTb = xT  + ((size_t)b << 20);
  const __bf16* vb  = val + ((size_t)b << 20);

  // Q: 32 rows/wave in registers, pre-scaled by C^-0.5 = 1/16 (exact)
  bf16x8 aq[2][8];
#pragma unroll
  for (int rg=0; rg<2; ++rg) {
    const __bf16* qp = xTb + (size_t)(q0 + qh*32 + rg*16 + l15)*256 + lhi*8;
#pragma unroll
    for (int kc=0; kc<8; ++kc) {
      bf16x8 v = *(const bf16x8*)(qp + kc*32);
#pragma unroll
      for (int j=0;j<8;++j) v[j] = (__bf16)((float)v[j] * 0.0625f);
      aq[rg][kc] = v;
    }
  }

  auto stage = [&](int buf, int m0) {
    char* kb = smem + buf*32768;
    char* vv = smem + 65536 + buf*32768;
#pragma unroll
    for (int i=0;i<4;++i) {          // K: 4 insts/wave (32 total)
      int inst = w*4 + i;
      int s = inst*64 + l;
      int row = s >> 5, cs = s & 31;
      const __bf16* g = xTb + (size_t)(m0 + row)*256 + ((cs ^ (row & 7)) << 3);
      async_copy16(kb + inst*1024, g);
    }
#pragma unroll
    for (int i=0;i<4;++i) {          // V: 4 insts/wave (32 total)
      int inst = w*4 + i;
      int s = inst*64 + l;
      int row = s >> 3, cs = s & 7;
      const __bf16* g = vb + (size_t)row*NPIX + m0 + ((cs ^ (row & 7)) << 3);
      async_copy16(vv + inst*1024, g);
    }
  };

  const f32x4 vzero = {0.f,0.f,0.f,0.f};
  float lsum[2][4];
#pragma unroll
  for (int rg=0;rg<2;++rg)
#pragma unroll
    for (int r=0;r<4;++r) lsum[rg][r] = 0.f;
  f32x4 o[2][8];
#pragma unroll
  for (int rg=0;rg<2;++rg)
#pragma unroll
    for (int cf=0; cf<8; ++cf) o[rg][cf] = vzero;

  stage(0, 0);

#pragma unroll 1
  for (int mt=0; mt<64; ++mt) {
    const int cur = mt & 1;
    asm volatile("s_waitcnt vmcnt(0)" ::: "memory");
    __builtin_amdgcn_s_barrier();
    __builtin_amdgcn_sched_barrier(0);
    if (mt < 63) stage(cur^1, (mt+1) << 6);   // flies under compute below

    const char* Kc = smem + cur*32768;
    const char* Vc = smem + 65536 + cur*32768;
    __bf16* pReg = (__bf16*)(smem + 131072 + (qh*2 + p)*2560); // [32q][40]

    // S = Q K^T : rows n = qh*32+rg*16+lhi*4+r, cols m = kvq*16+l15
    f32x4 s4[2];
    s4[0] = vzero; s4[1] = vzero;
    {
      const int krow = kvq*16 + l15;
      const char* kbase = Kc + krow*512;
#pragma unroll
      for (int kc=0; kc<8; ++kc) {
        bf16x8 bk = *(const bf16x8*)(kbase + ((((kc<<2)+lhi) ^ (krow&7)) << 4));
        s4[0] = __builtin_amdgcn_mfma_f32_16x16x32_bf16(aq[0][kc], bk, s4[0], 0,0,0);
        s4[1] = __builtin_amdgcn_mfma_f32_16x16x32_bf16(aq[1][kc], bk, s4[1], 0,0,0);
      }
    }

    // P = exp(S) -> pair-shared region (this wave's 16-kv half)
#pragma unroll
    for (int rg=0;rg<2;++rg)
#pragma unroll
      for (int r=0;r<4;++r) {
        float pv = __expf(s4[rg][r]);
        __bf16 pbf = (__bf16)pv;
        pReg[(rg*16 + lhi*4 + r)*40 + cfh*16 + l15] = pbf;
        lsum[rg][r] += (float)pbf;
      }

    // hand off P within kv-pair
    asm volatile("s_waitcnt lgkmcnt(0)" ::: "memory");
    __builtin_amdgcn_s_barrier();
    __builtin_amdgcn_sched_barrier(0);

    // full 32-kv P fragments (both halves of the pair)
    bf16x8 pa0 = *(const bf16x8*)(pReg + (size_t)l15*40 + lhi*8);
    bf16x8 pa1 = *(const bf16x8*)(pReg + (size_t)(16 + l15)*40 + lhi*8);

    // O += P V : cols c = cfh*128 + cf*16 + l15, K = pair's 32 kv
#pragma unroll
    for (int cf=0; cf<8; ++cf) {
      const int c = cfh*128 + (cf<<4) + l15;
      const char* vbase = Vc + c*128;
      bf16x8 bv = *(const bf16x8*)(vbase + ((((p<<2)+lhi) ^ (c&7)) << 4));
      o[0][cf] = __builtin_amdgcn_mfma_f32_16x16x32_bf16(pa0, bv, o[0][cf], 0,0,0);
      o[1][cf] = __builtin_amdgcn_mfma_f32_16x16x32_bf16(pa1, bv, o[1][cf], 0,0,0);
    }
  }

  // reduce lsum across the 16 l15 lanes (sum over this wave's 16 kv columns)
#pragma unroll
  for (int rg=0;rg<2;++rg)
#pragma unroll
    for (int r=0;r<4;++r)
#pragma unroll
      for (int d=1; d<16; d<<=1) lsum[rg][r] += __shfl_xor(lsum[rg][r], d, 64);

  __builtin_amdgcn_s_barrier();           // everyone done with K/V/P buffers
  float* oscr = (float*)smem;             // 4 regions (qh,cfh) x 32x128 f32
  float* lscr = (float*)(smem + 65536);   // 8 waves x 32 f32
  if (l15 == 0) {
#pragma unroll
    for (int rg=0;rg<2;++rg)
#pragma unroll
      for (int r=0;r<4;++r)
        lscr[w*32 + rg*16 + lhi*4 + r] = lsum[rg][r];
  }
  if (p == 1) {
    float* od = oscr + (size_t)(qh*2 + cfh)*4096;
#pragma unroll
    for (int rg=0;rg<2;++rg)
#pragma unroll
      for (int cf=0;cf<8;++cf)
#pragma unroll
        for (int r=0;r<4;++r)
          od[(rg*16 + lhi*4 + r)*128 + (cf<<4) + l15] = o[rg][cf][r];
  }
  asm volatile("s_waitcnt lgkmcnt(0)" ::: "memory");
  __builtin_amdgcn_s_barrier();
  if (p == 0) {
    const float* od = oscr + (size_t)(qh*2 + cfh)*4096;
    __bf16* Ob = O + ((size_t)b << 20);
#pragma unroll
    for (int rg=0;rg<2;++rg) {
      float inv[4];
#pragma unroll
      for (int r=0;r<4;++r) {
        float tot = 0.f;
#pragma unroll
        for (int k=0;k<4;++k)
          tot += lscr[(qh + 2*k)*32 + rg*16 + lhi*4 + r];
        inv[r] = 1.f / tot;
      }
#pragma unroll
      for (int cf=0;cf<8;++cf) {
        const int c = cfh*128 + (cf<<4) + l15;
        const float sc = scale[c], sh = shift[c];
#pragma unroll
        for (int r=0;r<4;++r) {
          float vtot = o[rg][cf][r] + od[(rg*16 + lhi*4 + r)*128 + (cf<<4) + l15];
          int row = q0 + qh*32 + rg*16 + lhi*4 + r;
          Ob[(size_t)row*256 + c] = (__bf16)(vtot * inv[r] * sc + sh);
        }
      }
    }
  }
}

extern "C" void kernel_launch(void* const* d_in, const int* in_sizes, int n_in,
                              void* d_out, int out_size, void* d_ws, size_t ws_size,
                              hipStream_t stream)
{
  const float* x     = (const float*)d_in[0];
  const float* wv    = (const float*)d_in[1];
  // d_in[2] = bv: bias shifts BN mean by the same amount -> cancels exactly
  const float* gv    = (const float*)d_in[3];
  const float* betav = (const float*)d_in[4];
  const float* ww    = (const float*)d_in[5];
  // d_in[6] = bw: cancels likewise
  const float* gw    = (const float*)d_in[7];
  const float* betaw = (const float*)d_in[8];
  float* out = (float*)d_out;

  char* ws = (char*)d_ws;
  __bf16* xT     = (__bf16*)(ws);                 // 8 MiB [B][N][C]
  __bf16* Obuf   = (__bf16*)(ws + 8388608);       // 8 MiB [B][N][C]
  __bf16* ybuf   = (__bf16*)(ws + 16777216);      // 8 MiB [B][C][N] conv out
  __bf16* wvt    = (__bf16*)(ws + 25165824);      // 1.125 MiB [9][O][I]
  __bf16* wwt    = (__bf16*)(ws + 26345472);      // 1.125 MiB
  float* scale_v = (float*)(ws + 27525120);
  float* shift_v = (float*)(ws + 27526144);
  float* scale_w = (float*)(ws + 27527168);
  float* shift_w = (float*)(ws + 27528192);
  __bf16* zbuf   = (__bf16*)(ws + 27529216);      // 1 KiB zero page
  if (ws_size < 27530240) return;

  hipMemsetAsync(zbuf, 0, 1024, stream);

  // transpose+cast (blocks 0..1023) + weight cast (blocks 1024..3327)
  k_prep<<<3328, 256, 0, stream>>>(x, xT, wv, ww, wvt, wwt);

  // value branch: conv1 + BN stats (apply fused into attn epilogue)
  k_conv_tap<<<256, 512, 0, stream>>>(wvt, xT, zbuf, ybuf);
  k_bn_stats<<<256, 256, 0, stream>>>(ybuf, gv, betav, scale_v, shift_v);

  // attention (consumes raw conv1 out + BN scale/shift)
  k_attn<<<256, 512, 0, stream>>>(xT, ybuf, scale_v, shift_v, Obuf);

  // output branch: conv2 + BN + relu
  k_conv_tap<<<256, 512, 0, stream>>>(wwt, Obuf, zbuf, ybuf);
  k_bn_stats<<<256, 256, 0, stream>>>(ybuf, gw, betaw, scale_w, shift_w);
  k_bn_relu<<<2048, 256, 0, stream>>>(ybuf, scale_w, shift_w, out);
}